// Round 5
// baseline (178.260 us; speedup 1.0000x reference)
//
#include <hip/hip_runtime.h>
#include <string.h>

// x = [32, 3, 512, 512] fp32, scale_factors = [2] fp32. Output same shape as x.
#define BD 32
#define CD 3
#define HD 512
#define WD 512
#define TH 8   // output rows per block (general path)

// Separable bilinear grid-sample (diagonal affine, zeros padding,
// align_corners=False).
//
// ROUND 5 STRUCTURE: four structurally different shader copies (chunked,
// chunked+NT, fat 16xf4, interleaved grid-stride) all pinned at ~59-64 us
// for the identity case while the harness's write-only fill sustains
// 6.7 TB/s -> the shader engine itself is the limiter, not the shape.
// So: host-side hipMemcpyAsync(out, x) ALWAYS (it is exactly the identity
// result; driver D2D path is documented at ~85% of peak on this platform),
// followed by a fixup kernel:
//   - identity (sx==1 && sy==1, exact in fp32 for this geometry): exit.
//   - general: run the full separable path, overwriting every element of
//     out (the prior copy is dead work, correctness unaffected; x is not
//     modified by the copy, so reads are clean).
__global__ __launch_bounds__(256) void stn_kernel(const float* __restrict__ x,
                                                  const float* __restrict__ sf,
                                                  float* __restrict__ out) {
    const float sx = sf[0];
    const float sy = sf[1];

    // Identity transform: the D2D copy already produced the exact output.
    if (sx == 1.0f && sy == 1.0f) return;

    // ---------------- general separable path ----------------
    __shared__ float xh[TH][WD];  // 16 KB

    const int t     = threadIdx.x;      // 0..255
    const int plane = blockIdx.x;       // 0..95  (b*C + c)
    const int h0    = blockIdx.y * TH;  // 0..511 step TH

    const int rr = t >> 7;              // row-pair parity: 0/1 (wave-uniform)
    const int c4 = (t & 127) << 2;      // float4 column base, covers 512 cols

    const float* xp = x + (long long)plane * HD * WD;

    // ---- phase A: load 4 row-pairs (this thread's rows r = 2*rp + rr) ----
    float4 A[4], B[4];
    float  fy0v[4], fy1v[4];
#pragma unroll
    for (int rp = 0; rp < 4; ++rp) {
        int   h    = h0 + rp * 2 + rr;
        float ysn  = (2.0f * (float)h + 1.0f) / (float)HD - 1.0f;
        float iy   = ((sy * ysn + 1.0f) * (float)HD - 1.0f) * 0.5f;
        float iy0f = floorf(iy);
        float wy1  = iy - iy0f;
        int   iy0  = (int)iy0f;
        int   iy1  = iy0 + 1;
        fy0v[rp]   = (iy0 >= 0 && iy0 < HD) ? (1.0f - wy1) : 0.0f;
        fy1v[rp]   = (iy1 >= 0 && iy1 < HD) ? wy1 : 0.0f;
        int iy0c   = min(max(iy0, 0), HD - 1);
        int iy1c   = min(max(iy1, 0), HD - 1);
        A[rp] = *(const float4*)(xp + (long long)iy0c * WD + c4);
        // zero-weight row contributes nothing: skip the global load
        // (h is wave-uniform -> clean s_cbranch, no divergence cost)
        if (fy1v[rp] != 0.0f) {
            B[rp] = *(const float4*)(xp + (long long)iy1c * WD + c4);
        } else {
            B[rp] = make_float4(0.0f, 0.0f, 0.0f, 0.0f);
        }
    }
#pragma unroll
    for (int rp = 0; rp < 4; ++rp) {
        int    r = rp * 2 + rr;
        float4 c;
        c.x = A[rp].x * fy0v[rp] + B[rp].x * fy1v[rp];
        c.y = A[rp].y * fy0v[rp] + B[rp].y * fy1v[rp];
        c.z = A[rp].z * fy0v[rp] + B[rp].z * fy1v[rp];
        c.w = A[rp].w * fy0v[rp] + B[rp].w * fy1v[rp];
        *(float4*)&xh[r][c4] = c;
    }
    __syncthreads();

    // ---- phase B: W interpolation — index math once, gather for all rows ----
    int   ix0c[2], ix1c[2];
    float fx0[2], fx1[2];
#pragma unroll
    for (int j = 0; j < 2; ++j) {
        int   w    = 2 * t + j;
        float xsn  = (2.0f * (float)w + 1.0f) / (float)WD - 1.0f;
        float ix   = ((sx * xsn + 1.0f) * (float)WD - 1.0f) * 0.5f;
        float ix0f = floorf(ix);
        float wx1  = ix - ix0f;
        int   ix0  = (int)ix0f;
        int   ix1  = ix0 + 1;
        fx0[j]     = (ix0 >= 0 && ix0 < WD) ? (1.0f - wx1) : 0.0f;
        fx1[j]     = (ix1 >= 0 && ix1 < WD) ? wx1 : 0.0f;
        ix0c[j]    = min(max(ix0, 0), WD - 1);
        ix1c[j]    = min(max(ix1, 0), WD - 1);
    }

    float* outp = out + ((long long)plane * HD + h0) * WD;
#pragma unroll
    for (int r = 0; r < TH; ++r) {
        float2 o;
        o.x = xh[r][ix0c[0]] * fx0[0] + xh[r][ix1c[0]] * fx1[0];
        o.y = xh[r][ix0c[1]] * fx0[1] + xh[r][ix1c[1]] * fx1[1];
        ((float2*)(outp + (long long)r * WD))[t] = o;
    }
}

extern "C" void kernel_launch(void* const* d_in, const int* in_sizes, int n_in,
                              void* d_out, int out_size, void* d_ws, size_t ws_size,
                              hipStream_t stream) {
    const float* x  = (const float*)d_in[0];
    const float* sf = (const float*)d_in[1];
    float* out      = (float*)d_out;

    // Always copy x -> out via the driver D2D path (SDMA/blit). For the
    // identity transform this IS the answer; otherwise the fixup kernel
    // overwrites every element. (hipMemcpyAsync on the capture stream is
    // harness-legal; x is never modified, so ordering is safe.)
    const size_t nbytes = (size_t)BD * CD * HD * WD * sizeof(float);
    hipMemcpyAsync(out, x, nbytes, hipMemcpyDeviceToDevice, stream);

    dim3 grid(BD * CD, HD / TH);  // 96 x 64 = 6144 blocks
    stn_kernel<<<grid, 256, 0, stream>>>(x, sf, out);
}

// Round 6
// 175.574 us; speedup vs baseline: 1.0153x; 1.0153x over previous
//
#include <hip/hip_runtime.h>

// x = [32, 3, 512, 512] fp32, scale_factors = [2] fp32. Output same shape as x.
#define BD 32
#define CD 3
#define HD 512
#define WD 512
#define TH 8   // output rows per block (general path)

typedef float f4 __attribute__((ext_vector_type(4)));

// Separable bilinear grid-sample (diagonal affine, zeros padding,
// align_corners=False).
//
// FINAL STRUCTURE (reverted to best-measured, rounds 1/2 = 176.0 us):
//
// FAST PATH (sx==1 && sy==1): the normalized-coord arithmetic is exact in
// fp32 (odd numerators <= 1023 over power-of-2 denominators), so ix==w,
// iy==h, all fractional weights are exactly 0 -> the op is the identity:
// a straight float4 copy, 256 threads x 4 float4 per block.
//   Copy-shape space exhausted (all ~59-63 us for 151 MB HBM traffic):
//   - chunked 4xf4 + NT stores:        58.6 us
//   - chunked 4xf4 + plain stores:     58.6 us (NT A/B = zero)
//   - fat 64KB blocks, 16xf4, RRRR/WWWW: 63.3 us (dead blocks cut waves)
//   - grid-stride interleaved (m13 shape): 59.0 us
//   - driver hipMemcpyAsync D2D blit:  ~58 us  <- external known-good, TIES
//   => mixed 100MB-read+100MB-write stream runs at ~2.5 TB/s HBM on this
//   part in this harness context (LLC half-thrashed by the 402 MB poison
//   fill: FETCH_SIZE shows only ~50 MB of the 100 MB read hits HBM).
//   This is the roofline; the write-only fill's 6.7 TB/s is not reachable
//   for a copy.
//
// GENERAL PATH: H-interp -> LDS stage -> W-gather, with wave-uniform skip
// of zero-weight global loads.
__global__ __launch_bounds__(256) void stn_kernel(const float* __restrict__ x,
                                                  const float* __restrict__ sf,
                                                  float* __restrict__ out) {
    const float sx = sf[0];
    const float sy = sf[1];
    const int   t  = threadIdx.x;  // 0..255

    if (sx == 1.0f && sy == 1.0f) {
        // identity transform -> exact copy.
        // 96 x 64 = 6144 blocks, each copies a contiguous 16 KB chunk:
        // 256 threads x 4 float4 (64 B/thread).
        const long long base =
            ((long long)blockIdx.y * gridDim.x + blockIdx.x) * 1024LL + t;
        const f4* __restrict__ src = (const f4*)x + base;
        f4* __restrict__ dst       = (f4*)out + base;
        f4 a = src[0];
        f4 b = src[256];
        f4 c = src[512];
        f4 d = src[768];
        dst[0]   = a;
        dst[256] = b;
        dst[512] = c;
        dst[768] = d;
        return;
    }

    // ---------------- general separable path ----------------
    __shared__ float xh[TH][WD];  // 16 KB

    const int plane = blockIdx.x;       // 0..95  (b*C + c)
    const int h0    = blockIdx.y * TH;  // 0..511 step TH

    const int rr = t >> 7;              // row-pair parity: 0/1 (wave-uniform)
    const int c4 = (t & 127) << 2;      // float4 column base, covers 512 cols

    const float* xp = x + (long long)plane * HD * WD;

    // ---- phase A: load 4 row-pairs (this thread's rows r = 2*rp + rr) ----
    float4 A[4], B[4];
    float  fy0v[4], fy1v[4];
#pragma unroll
    for (int rp = 0; rp < 4; ++rp) {
        int   h    = h0 + rp * 2 + rr;
        float ysn  = (2.0f * (float)h + 1.0f) / (float)HD - 1.0f;
        float iy   = ((sy * ysn + 1.0f) * (float)HD - 1.0f) * 0.5f;
        float iy0f = floorf(iy);
        float wy1  = iy - iy0f;
        int   iy0  = (int)iy0f;
        int   iy1  = iy0 + 1;
        fy0v[rp]   = (iy0 >= 0 && iy0 < HD) ? (1.0f - wy1) : 0.0f;
        fy1v[rp]   = (iy1 >= 0 && iy1 < HD) ? wy1 : 0.0f;
        int iy0c   = min(max(iy0, 0), HD - 1);
        int iy1c   = min(max(iy1, 0), HD - 1);
        A[rp] = *(const float4*)(xp + (long long)iy0c * WD + c4);
        // zero-weight row contributes nothing: skip the global load
        // (h is wave-uniform -> clean s_cbranch, no divergence cost)
        if (fy1v[rp] != 0.0f) {
            B[rp] = *(const float4*)(xp + (long long)iy1c * WD + c4);
        } else {
            B[rp] = make_float4(0.0f, 0.0f, 0.0f, 0.0f);
        }
    }
#pragma unroll
    for (int rp = 0; rp < 4; ++rp) {
        int    r = rp * 2 + rr;
        float4 c;
        c.x = A[rp].x * fy0v[rp] + B[rp].x * fy1v[rp];
        c.y = A[rp].y * fy0v[rp] + B[rp].y * fy1v[rp];
        c.z = A[rp].z * fy0v[rp] + B[rp].z * fy1v[rp];
        c.w = A[rp].w * fy0v[rp] + B[rp].w * fy1v[rp];
        *(float4*)&xh[r][c4] = c;
    }
    __syncthreads();

    // ---- phase B: W interpolation — index math once, gather for all rows ----
    int   ix0c[2], ix1c[2];
    float fx0[2], fx1[2];
#pragma unroll
    for (int j = 0; j < 2; ++j) {
        int   w    = 2 * t + j;
        float xsn  = (2.0f * (float)w + 1.0f) / (float)WD - 1.0f;
        float ix   = ((sx * xsn + 1.0f) * (float)WD - 1.0f) * 0.5f;
        float ix0f = floorf(ix);
        float wx1  = ix - ix0f;
        int   ix0  = (int)ix0f;
        int   ix1  = ix0 + 1;
        fx0[j]     = (ix0 >= 0 && ix0 < WD) ? (1.0f - wx1) : 0.0f;
        fx1[j]     = (ix1 >= 0 && ix1 < WD) ? wx1 : 0.0f;
        ix0c[j]    = min(max(ix0, 0), WD - 1);
        ix1c[j]    = min(max(ix1, 0), WD - 1);
    }

    float* outp = out + ((long long)plane * HD + h0) * WD;
#pragma unroll
    for (int r = 0; r < TH; ++r) {
        float2 o;
        o.x = xh[r][ix0c[0]] * fx0[0] + xh[r][ix1c[0]] * fx1[0];
        o.y = xh[r][ix0c[1]] * fx0[1] + xh[r][ix1c[1]] * fx1[1];
        ((float2*)(outp + (long long)r * WD))[t] = o;
    }
}

extern "C" void kernel_launch(void* const* d_in, const int* in_sizes, int n_in,
                              void* d_out, int out_size, void* d_ws, size_t ws_size,
                              hipStream_t stream) {
    const float* x  = (const float*)d_in[0];
    const float* sf = (const float*)d_in[1];
    float* out      = (float*)d_out;

    dim3 grid(BD * CD, HD / TH);  // 96 x 64 = 6144 blocks
    stn_kernel<<<grid, 256, 0, stream>>>(x, sf, out);
}